// Round 15
// baseline (73.231 us; speedup 1.0000x reference)
//
#include <hip/hip_runtime.h>

#define BB 65536
#define TT 20
#define NG16 4096             // 16-element groups
#define FR_ROW 160            // u32 per (g,t): 16 elems x 10 u32 (5 hf + 5 hb pairs)

#define WS_AF  0              // 9 A-frag tiles x 64 lanes x 4 u32 = 2304
#define WS_OLD 2304           // fallback 14-frag region (3584 u32)
#define WS_FR  8192           // [g][t][FR_ROW] u32 = 52.4 MB
#define PKB 0x00003C00u       // f16 pair {1.0, 0.0}

#define LOG2E  1.442695041f
#define LOG2E2 2.885390082f

// LDS write->punned-read ordering fence (guide rule #18): the h-exchange uses
// __fp16 stores re-read as punned u32 -- TBAA says no-alias, and DS ops can
// complete OOO.  Force both compiler order ("memory") and HW completion.
#define LDS_FENCE() do { asm volatile("s_waitcnt lgkmcnt(0)" ::: "memory"); \
                         __builtin_amdgcn_sched_barrier(0); } while (0)

typedef unsigned u32;
typedef __fp16 f16x8 __attribute__((ext_vector_type(8)));
typedef float   f32x16 __attribute__((ext_vector_type(16)));
typedef float   f32x4v __attribute__((ext_vector_type(4)));
typedef u32     u32x4 __attribute__((ext_vector_type(4)));
typedef __fp16  h2v   __attribute__((ext_vector_type(2)));

__device__ __forceinline__ u32 pk_h16(float a, float b) {
    h2v v = __builtin_amdgcn_cvt_pkrtz(a, b);
    return __builtin_bit_cast(u32, v);
}
__device__ __forceinline__ f32x4v MFMA16(u32x4 a, u32x4 b, f32x4v c) {
    return __builtin_amdgcn_mfma_f32_16x16x32_f16(
        __builtin_bit_cast(f16x8, a), __builtin_bit_cast(f16x8, b), c, 0, 0, 0);
}
__device__ __forceinline__ f32x16 MFMA32(u32x4 a, u32x4 b, f32x16 c) {
    return __builtin_amdgcn_mfma_f32_32x32x16_f16(
        __builtin_bit_cast(f16x8, a), __builtin_bit_cast(f16x8, b), c, 0, 0, 0);
}

// Combined-rcp LSTM unit (8 trans ops/unit). Gate order i,f,g,o.
__device__ __forceinline__ void unit_cr(float ai, float af, float ag, float ao,
                                        float* c, float* h) {
    float pi = __builtin_amdgcn_exp2f(-LOG2E * ai);
    float pf = __builtin_amdgcn_exp2f(-LOG2E * af);
    float q  = __builtin_amdgcn_exp2f(LOG2E2 * ag);
    float fv = __builtin_amdgcn_rcpf(1.0f + pf);
    float ig = (q - 1.0f) * __builtin_amdgcn_rcpf((1.0f + pi) * (q + 1.0f));
    float cv = fmaf(fv, *c, ig);
    *c = cv;
    float po = __builtin_amdgcn_exp2f(-LOG2E * ao);
    float qc = __builtin_amdgcn_exp2f(LOG2E2 * cv);
    *h = (qc - 1.0f) * __builtin_amdgcn_rcpf((1.0f + po) * (qc + 1.0f));
}

// =================== prep (16x16x32 A-frags, blocked-16 map) ===================
// Layout per HW-verified tr_b16 (m156/m162): lane quarter q holds
// k in {4q..4q+3} U {16+4q..16+4q+3}; u32 j: k = (j>>1)*16 + 4q + (j&1)*2 + s.
// Rows: m = local_unit*4 + gate.  K-maps: fwd/bwd: x@k0-5, bias@k6, h@k8-17.
// cb: hf@k0-9, hb@k10-19, h1@k20-29, bias@k30.
__global__ __launch_bounds__(256)
void prep16(
    const float* __restrict__ wih0, const float* __restrict__ whh0,
    const float* __restrict__ bih0, const float* __restrict__ bhh0,
    const float* __restrict__ wih0r,const float* __restrict__ whh0r,
    const float* __restrict__ bih0r,const float* __restrict__ bhh0r,
    const float* __restrict__ wih1r,const float* __restrict__ whh1r,
    const float* __restrict__ bih1r,const float* __restrict__ bhh1r,
    u32* __restrict__ ws)
{
    for (int gid = threadIdx.x; gid < 9 * 64 * 4; gid += 256) {
        int fid = gid >> 8;            // 0..8 = ct*3 + T
        int ct = fid / 3, T = fid % 3;
        int l = (gid >> 2) & 63, j = gid & 3;
        int m = l & 15, qq = l >> 4;
        int unit = T * 4 + (m >> 2), gate = m & 3;
        float v[2] = {0.f, 0.f};
        if (unit <= 9) {
            int orow = gate * 10 + unit;
#pragma unroll
            for (int s = 0; s < 2; ++s) {
                int k = (j >> 1) * 16 + 4 * qq + (j & 1) * 2 + s;
                float val = 0.f;
                if (ct < 2) {
                    const float* wih = ct ? wih0r : wih0;
                    const float* whh = ct ? whh0r : whh0;
                    if (k < 6)            val = wih[orow * 6 + k];
                    else if (k == 6)      val = ct ? (bih0r[orow] + bhh0r[orow])
                                               : (bih0[orow] + bhh0[orow]);
                    else if (k >= 8 && k <= 17) val = whh[orow * 10 + (k - 8)];
                } else {
                    if (k < 20)           val = wih1r[orow * 20 + k];
                    else if (k <= 29)     val = whh1r[orow * 10 + (k - 20)];
                    else if (k == 30)     val = bih1r[orow] + bhh1r[orow];
                }
                v[s] = val;
            }
        }
        ws[WS_AF + (fid * 64 + l) * 4 + j] = pk_h16(v[0], v[1]);
    }
}

// =================== main: 4 waves x 16 elems, zero barriers ===================
struct Lds16 {
    uint2 bx[4][TT][16][2];             // 20480 B  [0]={x01,x23} [1]={x45,PKB}
    float m[4][TT][16];                 //  5120 B  mask
    unsigned short hx[4][2][16][12];    //  3072 B  h exchange (f16), [F/B][e][unit]
    u32   zpad[2];                      //     8 B  always-zero words
};

__global__ __launch_bounds__(256, 4)
void bilstm16(
    const int*   __restrict__ eidx, const float* __restrict__ f,
    const float* __restrict__ emb,  const float* __restrict__ fw,
    const float* __restrict__ fb,
    const u32* __restrict__ wsr, u32* __restrict__ fr,
    float* __restrict__ out)
{
    __shared__ Lds16 lds;
    const int tid  = threadIdx.x;
    const int lane = tid & 63;
    const int e    = lane & 15;
    const int q    = lane >> 4;
    const int wv   = __builtin_amdgcn_readfirstlane(tid >> 6);
    const int g    = blockIdx.x * 4 + wv;
    const int b0   = g * 16;
    const int be   = e * 24;
    u32* frp = fr + (size_t)g * TT * FR_ROW;

    // ---- wave-local staging ----
    {
        float fw0=fw[0],fw1=fw[1],fw2=fw[2],fw3=fw[3],fw4=fw[4];
        float fw5=fw[5],fw6=fw[6],fw7=fw[7],fw8=fw[8];
        float fb0=fb[0],fb1=fb[1],fb2=fb[2];
#pragma unroll 1
        for (int it = 0; it < 5; ++it) {
            int idx = lane + it * 64;              // 0..319
            int ee = idx / TT, t = idx - ee * TT;
            int gi = (b0 + ee) * TT + t;
            float f0 = f[gi * 3], f1 = f[gi * 3 + 1], f2v = f[gi * 3 + 2];
            int ei = eidx[gi] * 3;
            float x0 = emb[ei], x1 = emb[ei + 1], x2 = emb[ei + 2];
            float x3 = fmaf(fw0, f0, fmaf(fw1, f1, fmaf(fw2, f2v, fb0)));
            float x4 = fmaf(fw3, f0, fmaf(fw4, f1, fmaf(fw5, f2v, fb1)));
            float x5 = fmaf(fw6, f0, fmaf(fw7, f1, fmaf(fw8, f2v, fb2)));
            lds.bx[wv][t][ee][0] = make_uint2(pk_h16(x0, x1), pk_h16(x2, x3));
            lds.bx[wv][t][ee][1] = make_uint2(pk_h16(x4, x5), PKB);
            lds.m[wv][t][ee]     = (f1 != 0.f) ? 1.f : 0.f;
        }
        u32* zz = (u32*)&lds.hx[wv][0][0][0];      // zero both h buffers (768 B)
        zz[lane] = 0u; zz[lane + 64] = 0u; zz[lane + 128] = 0u;
        if (lane < 2) lds.zpad[lane] = 0u;
    }
    LDS_FENCE();

    char* bxb  = (char*)&lds.bx[wv][0][e][0];
    char* hxFb = (char*)&lds.hx[wv][0][0][0];
    char* hxBb = (char*)&lds.hx[wv][1][0][0];
    char* hxF  = hxFb + be;
    char* hxB  = hxBb + be;
    char* zp   = (char*)lds.zpad;
    // h-write offsets: units q, 4+q, 8+q (pads 10/11 for q>=2)
    const int uw0 = be + 2 * q, uw1 = be + 8 + 2 * q, uw2 = be + 16 + 2 * q;

    const u32x4* wv4 = (const u32x4*)(wsr + WS_AF);
    const f32x4v z4 = {};

    // ---- Phase A: fwd + bwd layer-0 chains, interleaved in-wave ----
    // B = blocked-16: lane q covers k {4q..4q+3} (b[0],b[1]) and
    // {16+4q..16+4q+3} (b[2],b[3]).
    {
        u32x4 F0 = wv4[0 * 64 + lane], F1 = wv4[1 * 64 + lane], F2 = wv4[2 * 64 + lane];
        u32x4 G0 = wv4[3 * 64 + lane], G1 = wv4[4 * 64 + lane], G2 = wv4[5 * 64 + lane];
        // b-frag word addresses (select-free): q<2 -> staged x; q>=2 -> h exchange
        const char* aF  = (q < 2) ? (bxb + q * 8) : (hxF + (q - 2) * 8);
        const char* aB  = (q < 2) ? (bxb + q * 8 + 19 * 256) : (hxB + (q - 2) * 8);
        const char* a2F = (q == 0) ? (hxF + 16) : zp;
        const char* a2B = (q == 0) ? (hxB + 16) : zp;
        const int   strA = (q < 2) ? 256 : 0;

        float cF[3] = {0,0,0}, cB[3] = {0,0,0};
#pragma unroll 1
        for (int s = 0; s < TT; ++s) {
            // fwd cell t=s
            uint2 uF = *(const uint2*)(aF + s * strA);
            u32   wF = *(const u32*)a2F;
            u32x4 bf; bf[0] = uF.x; bf[1] = uF.y; bf[2] = wF; bf[3] = 0u;
            f32x4v A0 = MFMA16(F0, bf, z4), A1 = MFMA16(F1, bf, z4), A2 = MFMA16(F2, bf, z4);
            // bwd cell t=19-s
            uint2 uB = *(const uint2*)(aB - s * strA);
            u32   wB = *(const u32*)a2B;
            u32x4 bb; bb[0] = uB.x; bb[1] = uB.y; bb[2] = wB; bb[3] = 0u;
            f32x4v C0 = MFMA16(G0, bb, z4), C1 = MFMA16(G1, bb, z4), C2 = MFMA16(G2, bb, z4);
            // updates: units q, 4+q, 8+q(q<2; pad otherwise)
            float hF[3], hB[3];
            unit_cr(A0[0], A0[1], A0[2], A0[3], &cF[0], &hF[0]);
            unit_cr(A1[0], A1[1], A1[2], A1[3], &cF[1], &hF[1]);
            unit_cr(A2[0], A2[1], A2[2], A2[3], &cF[2], &hF[2]);
            unit_cr(C0[0], C0[1], C0[2], C0[3], &cB[0], &hB[0]);
            unit_cr(C1[0], C1[1], C1[2], C1[3], &cB[1], &hB[1]);
            unit_cr(C2[0], C2[1], C2[2], C2[3], &cB[2], &hB[2]);
            *(__fp16*)(hxFb + uw0) = (__fp16)hF[0];
            *(__fp16*)(hxFb + uw1) = (__fp16)hF[1];
            *(__fp16*)(hxFb + uw2) = (__fp16)hF[2];
            *(__fp16*)(hxBb + uw0) = (__fp16)hB[0];
            *(__fp16*)(hxBb + uw1) = (__fp16)hB[1];
            *(__fp16*)(hxBb + uw2) = (__fp16)hB[2];
            LDS_FENCE();   // order f16 h-stores vs punned u32 reads (exports + next t)
            // export CB-ready pairs: hf -> slots e*10+{0..4}, hb -> e*10+{5..9}
            u32* frT = frp + s * FR_ROW;
            u32* frB = frp + (TT - 1 - s) * FR_ROW;
            frT[e * 10 + q]     = *(u32*)(hxF + q * 4);
            frB[e * 10 + 5 + q] = *(u32*)(hxB + q * 4);
            if (q == 0) {
                frT[e * 10 + 4] = *(u32*)(hxF + 16);
                frB[e * 10 + 9] = *(u32*)(hxB + 16);
            }
        }
    }

    // ---- Phase B: layer-1 backward (K: hf0-9 | hb0-9 | h1 | bias) ----
    {
        u32x4 H0 = wv4[6 * 64 + lane], H1 = wv4[7 * 64 + lane], H2 = wv4[8 * 64 + lane];
        // re-zero h1 buffer (hx[wv][0], 96 u32)
        u32* hz = (u32*)hxFb;
        hz[lane] = 0u;
        if (lane < 32) hz[64 + lane] = 0u;
        LDS_FENCE();
        const char* caddr = (q == 0) ? zp : (hxF + (q - 1) * 8);
        const int loffA = e * 10 + q * 2;     // uint2 slot pairs {0,1},{2,3},{4,5},{6,7}
        const int loffB = e * 10 + 8;         // slots {8,9} (hb67, hb89; q==0 only)
        float cH[3] = {0,0,0}, tot = 0.f;
        uint2 La = *(const uint2*)(frp + (TT - 1) * FR_ROW + loffA);
        uint2 Lb = *(const uint2*)(frp + (TT - 1) * FR_ROW + loffB);
#pragma unroll 1
        for (int t = TT - 1; t >= 0; --t) {
            uint2 C = *(const uint2*)caddr;   // h1 pairs (q>=1) / zeros (q==0)
            u32x4 bc;
            bc[0] = La.x;
            bc[1] = La.y;
            bc[2] = (q == 0) ? Lb.x : C.x;
            bc[3] = (q == 0) ? Lb.y : ((q == 3) ? PKB : C.y);
            if (t > 0) {                      // prefetch t-1
                La = *(const uint2*)(frp + (t - 1) * FR_ROW + loffA);
                Lb = *(const uint2*)(frp + (t - 1) * FR_ROW + loffB);
            }
            f32x4v D0 = MFMA16(H0, bc, z4), D1 = MFMA16(H1, bc, z4), D2 = MFMA16(H2, bc, z4);
            float hH[3];
            unit_cr(D0[0], D0[1], D0[2], D0[3], &cH[0], &hH[0]);
            unit_cr(D1[0], D1[1], D1[2], D1[3], &cH[1], &hH[1]);
            unit_cr(D2[0], D2[1], D2[2], D2[3], &cH[2], &hH[2]);
            *(__fp16*)(hxFb + uw0) = (__fp16)hH[0];
            *(__fp16*)(hxFb + uw1) = (__fp16)hH[1];
            *(__fp16*)(hxFb + uw2) = (__fp16)hH[2];
            LDS_FENCE();   // order h1 f16 stores vs next-t punned reads
            if (q == 1) {                     // unit 9 = 8+q at q=1 -> hH[2]
                float ip = fmaxf(hH[2] * lds.m[wv][t][e], 0.f);
                out[BB + (b0 + e) * TT + t] = ip;
                tot += ip;
            }
        }
        if (q == 1) out[b0 + e] = tot;
    }
}

// =================== fallback (small ws): verified 32x32 r11 path ===================
__device__ __forceinline__ u32x4 pack_h32(const float* h, bool hi, int xaddr, u32 b3) {
    u32 send = hi ? pk_h16(h[3], h[4]) : __float_as_uint(h[4]);
    u32 recv = (u32)__builtin_amdgcn_ds_bpermute(xaddr, (int)send);
    u32 lo0 = pk_h16(h[0], h[1]), lo1 = pk_h16(h[2], h[3]);
    u32 hi0 = pk_h16(__uint_as_float(recv), h[0]);
    u32 hi1 = pk_h16(h[1], h[2]);
    u32x4 b;
    b[0] = hi ? hi0 : lo0; b[1] = hi ? hi1 : lo1;
    b[2] = hi ? 0u : recv; b[3] = b3;
    return b;
}
__device__ __forceinline__ void cell_update5(const f32x16 a0, const f32x16 a1,
                                             float* c, float* h) {
#pragma unroll
    for (int v = 0; v < 4; ++v)
        unit_cr(a0[v], a0[4 + v], a0[8 + v], a0[12 + v], &c[v], &h[v]);
    unit_cr(a1[0], a1[1], a1[2], a1[3], &c[4], &h[4]);
}
__device__ __forceinline__ int inv_pi(int row) {
    if (row < 32) { int q = row >> 3, rem = row & 7; return q * 10 + 5 * (rem >> 2) + (rem & 3); }
    if (row < 40) { int lo = row - 32; return (lo & 3) * 10 + 5 * (lo >> 2) + 4; }
    return -1;
}
__global__ __launch_bounds__(256)
void prep_old(
    const float* __restrict__ wih0, const float* __restrict__ whh0,
    const float* __restrict__ bih0, const float* __restrict__ bhh0,
    const float* __restrict__ wih0r,const float* __restrict__ whh0r,
    const float* __restrict__ bih0r,const float* __restrict__ bhh0r,
    const float* __restrict__ wih1r,const float* __restrict__ whh1r,
    const float* __restrict__ bih1r,const float* __restrict__ bhh1r,
    u32* __restrict__ ws)
{
    for (int gid = threadIdx.x; gid < 14 * 64 * 4; gid += 256) {
        int fid = gid >> 8, l = (gid >> 2) & 63, j = gid & 3;
        int gq = l >> 5;
        int tile, chunk;
        if (fid < 8) { tile = (fid >> 1) & 1; chunk = fid & 1; }
        else         { int q2 = fid - 8; tile = q2 / 3; chunk = q2 % 3; }
        int row = tile * 32 + (l & 31);
        int orow = inv_pi(row);
        int kb = (j >> 1) * 8 + 4 * gq + (j & 1) * 2;
        float v[2] = {0.f, 0.f};
        if (orow >= 0) {
#pragma unroll
            for (int s = 0; s < 2; ++s) {
                int k = kb + s;
                float val = 0.f;
                if (fid < 8) {
                    bool bwd = fid >= 4;
                    if (chunk == 0) {
                        if (k < 6)       val = (bwd ? wih0r : wih0)[orow * 6 + k];
                        else if (k == 6) val = (bwd ? bih0r[orow] + bhh0r[orow]
                                                    : bih0[orow] + bhh0[orow]);
                    } else { if (k < 10) val = (bwd ? whh0r : whh0)[orow * 10 + k]; }
                } else {
                    if (chunk == 0)      { if (k < 10) val = wih1r[orow * 20 + k]; }
                    else if (chunk == 1) { if (k < 10) val = wih1r[orow * 20 + 10 + k]; }
                    else {
                        if (k < 10)       val = whh1r[orow * 10 + k];
                        else if (k == 10) val = bih1r[orow] + bhh1r[orow];
                    }
                }
                v[s] = val;
            }
        }
        ws[WS_OLD + (fid * 64 + l) * 4 + j] = pk_h16(v[0], v[1]);
    }
}
struct LdsFB { u32 x[TT][3][32]; float m[TT][32]; u32 hf[TT][160]; };
__global__ __launch_bounds__(64)
void bilstm_fb(
    const int*   __restrict__ eidx, const float* __restrict__ f,
    const float* __restrict__ emb,  const float* __restrict__ fw,
    const float* __restrict__ fb,
    const u32* __restrict__ wsr, float* __restrict__ out)
{
    __shared__ LdsFB lds;
    const int  lane = threadIdx.x;
    const int  e    = lane & 31;
    const bool hi   = lane >= 32;
    const int  wid  = blockIdx.x;
    const int  b0   = wid * 32;
    const int  xaddr = (lane ^ 32) << 2;
    {
        float fw0=fw[0],fw1=fw[1],fw2=fw[2],fw3=fw[3],fw4=fw[4];
        float fw5=fw[5],fw6=fw[6],fw7=fw[7],fw8=fw[8];
        float fb0=fb[0],fb1=fb[1],fb2=fb[2];
#pragma unroll 1
        for (int it = 0; it < 10; ++it) {
            int idx = lane + it * 64;
            int ee = idx / 20, t = idx - ee * 20;
            int gi = (b0 + ee) * TT + t;
            float f0 = f[gi * 3], f1 = f[gi * 3 + 1], f2v = f[gi * 3 + 2];
            int ei = eidx[gi] * 3;
            float x0 = emb[ei], x1 = emb[ei + 1], x2 = emb[ei + 2];
            float x3 = fmaf(fw0, f0, fmaf(fw1, f1, fmaf(fw2, f2v, fb0)));
            float x4 = fmaf(fw3, f0, fmaf(fw4, f1, fmaf(fw5, f2v, fb1)));
            float x5 = fmaf(fw6, f0, fmaf(fw7, f1, fmaf(fw8, f2v, fb2)));
            lds.x[t][0][ee] = pk_h16(x0, x1);
            lds.x[t][1][ee] = pk_h16(x2, x3);
            lds.x[t][2][ee] = pk_h16(x4, x5);
            lds.m[t][ee]    = (f1 != 0.f) ? 1.f : 0.f;
        }
    }
    const u32x4* wv = (const u32x4*)(wsr + WS_OLD);
    const f32x16 zf = {};
    {
        u32x4 wf0 = wv[0 * 64 + lane], wf1 = wv[1 * 64 + lane];
        u32x4 wf2 = wv[2 * 64 + lane], wf3 = wv[3 * 64 + lane];
        float cf[5] = {0,0,0,0,0}, hv[5] = {0,0,0,0,0};
        u32x4 bx0;
        {
            u32 x01 = lds.x[0][0][e], x23 = lds.x[0][1][e], x45 = lds.x[0][2][e];
            bx0[0] = hi ? x45 : x01; bx0[1] = hi ? PKB : x23; bx0[2] = 0u; bx0[3] = 0u;
        }
        f32x16 a0x = MFMA32(wf0, bx0, zf);
        f32x16 a1x = MFMA32(wf2, bx0, zf);
        u32x4 bh;
#pragma unroll 1
        for (int t = 0; t < TT; ++t) {
            f32x16 a0 = a0x, a1 = a1x;
            if (t > 0) { a0 = MFMA32(wf1, bh, a0); a1 = MFMA32(wf3, bh, a1); }
            if (t + 1 < TT) {
                u32 x01 = lds.x[t+1][0][e], x23 = lds.x[t+1][1][e], x45 = lds.x[t+1][2][e];
                u32x4 bx; bx[0] = hi ? x45 : x01; bx[1] = hi ? PKB : x23; bx[2] = 0u; bx[3] = 0u;
                a0x = MFMA32(wf0, bx, zf);
                a1x = MFMA32(wf2, bx, zf);
            }
            cell_update5(a0, a1, cf, hv);
            bh = pack_h32(hv, hi, xaddr, 0u);
            lds.hf[t][lane * 2] = bh[0]; lds.hf[t][lane * 2 + 1] = bh[1];
            if (!hi) lds.hf[t][128 + e] = bh[2];
        }
    }
    {
        u32x4 wb0 = wv[4 * 64 + lane], wb1 = wv[5 * 64 + lane];
        u32x4 wb2 = wv[6 * 64 + lane], wb3 = wv[7 * 64 + lane];
        u32x4 wB0 = wv[8 * 64 + lane], wB1 = wv[9 * 64 + lane], wB2 = wv[10 * 64 + lane];
        u32x4 wB3 = wv[11 * 64 + lane], wB4 = wv[12 * 64 + lane], wB5 = wv[13 * 64 + lane];
        float cb[5] = {0,0,0,0,0}, hbv[5] = {0,0,0,0,0};
        float cc[5] = {0,0,0,0,0}, h1v[5] = {0,0,0,0,0};
        float tot = 0.f;
        {
            u32 x01 = lds.x[TT-1][0][e], x23 = lds.x[TT-1][1][e], x45 = lds.x[TT-1][2][e];
            u32x4 bx; bx[0] = hi ? x45 : x01; bx[1] = hi ? PKB : x23; bx[2] = 0u; bx[3] = 0u;
            f32x16 a0 = MFMA32(wb0, bx, zf);
            f32x16 a1 = MFMA32(wb2, bx, zf);
            cell_update5(a0, a1, cb, hbv);
        }
        uint2 cur2 = make_uint2(lds.hf[TT-1][lane * 2], lds.hf[TT-1][lane * 2 + 1]);
        u32   curw = lds.hf[TT-1][128 + e];
#pragma unroll 1
        for (int t = TT - 1; t >= 1; --t) {
            uint2 nxt2 = make_uint2(lds.hf[t-1][lane * 2], lds.hf[t-1][lane * 2 + 1]);
            u32   nxtw = lds.hf[t-1][128 + e];
            u32x4 shared = pack_h32(hbv, hi, xaddr, 0u);
            u32x4 bh1    = pack_h32(h1v, hi, xaddr, hi ? 0u : PKB);
            u32x4 bhf; bhf[0] = cur2.x; bhf[1] = cur2.y; bhf[2] = hi ? 0u : curw; bhf[3] = 0u;
            f32x16 B0 = MFMA32(wB0, bhf, zf); B0 = MFMA32(wB1, shared, B0); B0 = MFMA32(wB2, bh1, B0);
            f32x16 B1 = MFMA32(wB3, bhf, zf); B1 = MFMA32(wB4, shared, B1); B1 = MFMA32(wB5, bh1, B1);
            u32 x01 = lds.x[t-1][0][e], x23 = lds.x[t-1][1][e], x45 = lds.x[t-1][2][e];
            u32x4 bx; bx[0] = hi ? x45 : x01; bx[1] = hi ? PKB : x23; bx[2] = 0u; bx[3] = 0u;
            f32x16 A0 = MFMA32(wb0, bx, zf); A0 = MFMA32(wb1, shared, A0);
            f32x16 A1 = MFMA32(wb2, bx, zf); A1 = MFMA32(wb3, shared, A1);
            cell_update5(B0, B1, cc, h1v);
            if (hi) {
                float ip = fmaxf(h1v[4] * lds.m[t][e], 0.f);
                out[BB + (b0 + e) * TT + t] = ip;
                tot += ip;
            }
            cell_update5(A0, A1, cb, hbv);
            cur2 = nxt2; curw = nxtw;
        }
        {
            u32x4 shared = pack_h32(hbv, hi, xaddr, 0u);
            u32x4 bh1    = pack_h32(h1v, hi, xaddr, hi ? 0u : PKB);
            u32x4 bhf; bhf[0] = cur2.x; bhf[1] = cur2.y; bhf[2] = hi ? 0u : curw; bhf[3] = 0u;
            f32x16 B0 = MFMA32(wB0, bhf, zf); B0 = MFMA32(wB1, shared, B0); B0 = MFMA32(wB2, bh1, B0);
            f32x16 B1 = MFMA32(wB3, bhf, zf); B1 = MFMA32(wB4, shared, B1); B1 = MFMA32(wB5, bh1, B1);
            cell_update5(B0, B1, cc, h1v);
            if (hi) {
                float ip = fmaxf(h1v[4] * lds.m[0][e], 0.f);
                out[BB + (b0 + e) * TT + 0] = ip;
                tot += ip;
                out[b0 + e] = tot;
            }
        }
    }
}

extern "C" void kernel_launch(void* const* d_in, const int* in_sizes, int n_in,
                              void* d_out, int out_size, void* d_ws, size_t ws_size,
                              hipStream_t stream) {
    const int*   eidx  = (const int*)  d_in[0];
    const float* f     = (const float*)d_in[1];
    const float* emb   = (const float*)d_in[2];
    const float* fw    = (const float*)d_in[3];
    const float* fb    = (const float*)d_in[4];
    const float* wih0  = (const float*)d_in[5];
    const float* whh0  = (const float*)d_in[6];
    const float* bih0  = (const float*)d_in[7];
    const float* bhh0  = (const float*)d_in[8];
    const float* wih0r = (const float*)d_in[9];
    const float* whh0r = (const float*)d_in[10];
    const float* bih0r = (const float*)d_in[11];
    const float* bhh0r = (const float*)d_in[12];
    // d_in[13..16] = layer-1 forward weights: dead (output uses only bwd unit 9)
    const float* wih1r = (const float*)d_in[17];
    const float* whh1r = (const float*)d_in[18];
    const float* bih1r = (const float*)d_in[19];
    const float* bhh1r = (const float*)d_in[20];
    float* out = (float*)d_out;
    u32* ws = (u32*)d_ws;

    const size_t need16 = (size_t)(WS_FR + (size_t)NG16 * TT * FR_ROW + 64) * 4;
    if (ws_size >= need16) {
        hipLaunchKernelGGL(prep16, dim3(1), dim3(256), 0, stream,
                           wih0, whh0, bih0, bhh0, wih0r, whh0r, bih0r, bhh0r,
                           wih1r, whh1r, bih1r, bhh1r, ws);
        hipLaunchKernelGGL(bilstm16, dim3(NG16 / 4), dim3(256), 0, stream,
                           eidx, f, emb, fw, fb, ws, ws + WS_FR, out);
    } else {
        hipLaunchKernelGGL(prep_old, dim3(1), dim3(256), 0, stream,
                           wih0, whh0, bih0, bhh0, wih0r, whh0r, bih0r, bhh0r,
                           wih1r, whh1r, bih1r, bhh1r, ws);
        hipLaunchKernelGGL(bilstm_fb, dim3(BB / 32), dim3(64), 0, stream,
                           eidx, f, emb, fw, fb, ws, out);
    }
}

// Round 16
// 72.297 us; speedup vs baseline: 1.0129x; 1.0129x over previous
//
#include <hip/hip_runtime.h>

#define BB 65536
#define TT 20
#define NG16 4096             // 16-element groups
#define FR_ROW 160            // u32 per (g,t): 16 elems x 10 u32 (5 hf + 5 hb pairs)

#define WS_AF  0              // 9 A-frag tiles x 64 lanes x 4 u32 = 2304
#define WS_OLD 2304           // fallback 14-frag region (3584 u32)
#define WS_FR  8192           // [g][t][FR_ROW] u32 = 52.4 MB
#define PKB 0x00003C00u       // f16 pair {1.0, 0.0}

#define LOG2E  1.442695041f
#define LOG2E2 2.885390082f

typedef unsigned u32;
typedef __fp16 f16x8 __attribute__((ext_vector_type(8)));
typedef float   f32x16 __attribute__((ext_vector_type(16)));
typedef float   f32x4v __attribute__((ext_vector_type(4)));
typedef u32     u32x4 __attribute__((ext_vector_type(4)));
typedef __fp16  h2v   __attribute__((ext_vector_type(2)));

__device__ __forceinline__ u32 pk_h16(float a, float b) {
    h2v v = __builtin_amdgcn_cvt_pkrtz(a, b);
    return __builtin_bit_cast(u32, v);
}
__device__ __forceinline__ f32x4v MFMA16(u32x4 a, u32x4 b, f32x4v c) {
    return __builtin_amdgcn_mfma_f32_16x16x32_f16(
        __builtin_bit_cast(f16x8, a), __builtin_bit_cast(f16x8, b), c, 0, 0, 0);
}
__device__ __forceinline__ f32x16 MFMA32(u32x4 a, u32x4 b, f32x16 c) {
    return __builtin_amdgcn_mfma_f32_32x32x16_f16(
        __builtin_bit_cast(f16x8, a), __builtin_bit_cast(f16x8, b), c, 0, 0, 0);
}

// Combined-rcp LSTM unit (8 trans ops/unit). Gate order i,f,g,o.
__device__ __forceinline__ void unit_cr(float ai, float af, float ag, float ao,
                                        float* c, float* h) {
    float pi = __builtin_amdgcn_exp2f(-LOG2E * ai);
    float pf = __builtin_amdgcn_exp2f(-LOG2E * af);
    float q  = __builtin_amdgcn_exp2f(LOG2E2 * ag);
    float fv = __builtin_amdgcn_rcpf(1.0f + pf);
    float ig = (q - 1.0f) * __builtin_amdgcn_rcpf((1.0f + pi) * (q + 1.0f));
    float cv = fmaf(fv, *c, ig);
    *c = cv;
    float po = __builtin_amdgcn_exp2f(-LOG2E * ao);
    float qc = __builtin_amdgcn_exp2f(LOG2E2 * cv);
    *h = (qc - 1.0f) * __builtin_amdgcn_rcpf((1.0f + po) * (qc + 1.0f));
}

// =================== prep (16x16x32 A-frags, blocked-16 map) ===================
// k-map (r15-verified): lane quarter qq holds k in {4qq..4qq+3} U
// {16+4qq..16+4qq+3}; u32 j: k = (j>>1)*16 + 4qq + (j&1)*2 + s.
// Row permutation (NEW): tile T, row m: mq=m>>2, gate=m&3;
//   T=0 -> unit 2mq, T=1 -> unit 2mq+1, T=2 -> unit 8+mq (mq<2), else pad.
// => lane quarter q owns units {2q, 2q+1, 8+q}: first two are ADJACENT, so
// the h-exchange is pure u32 pair-slots (no f16/u32 punning, no fences).
// K-maps: fwd/bwd: x@k0-5, bias@k6, h@k8-17.  cb: hf@k0-9, hb@k10-19,
// h1@k20-29, bias@k30.
__global__ __launch_bounds__(256)
void prep16(
    const float* __restrict__ wih0, const float* __restrict__ whh0,
    const float* __restrict__ bih0, const float* __restrict__ bhh0,
    const float* __restrict__ wih0r,const float* __restrict__ whh0r,
    const float* __restrict__ bih0r,const float* __restrict__ bhh0r,
    const float* __restrict__ wih1r,const float* __restrict__ whh1r,
    const float* __restrict__ bih1r,const float* __restrict__ bhh1r,
    u32* __restrict__ ws)
{
    for (int gid = threadIdx.x; gid < 9 * 64 * 4; gid += 256) {
        int fid = gid >> 8;            // 0..8 = ct*3 + T
        int ct = fid / 3, T = fid % 3;
        int l = (gid >> 2) & 63, j = gid & 3;
        int m = l & 15, qq = l >> 4;
        int mq = m >> 2, gate = m & 3;
        int unit;
        if (T == 0)      unit = 2 * mq;
        else if (T == 1) unit = 2 * mq + 1;
        else             unit = (mq < 2) ? (8 + mq) : 99;
        float v[2] = {0.f, 0.f};
        if (unit <= 9) {
            int orow = gate * 10 + unit;
#pragma unroll
            for (int s = 0; s < 2; ++s) {
                int k = (j >> 1) * 16 + 4 * qq + (j & 1) * 2 + s;
                float val = 0.f;
                if (ct < 2) {
                    const float* wih = ct ? wih0r : wih0;
                    const float* whh = ct ? whh0r : whh0;
                    if (k < 6)            val = wih[orow * 6 + k];
                    else if (k == 6)      val = ct ? (bih0r[orow] + bhh0r[orow])
                                               : (bih0[orow] + bhh0[orow]);
                    else if (k >= 8 && k <= 17) val = whh[orow * 10 + (k - 8)];
                } else {
                    if (k < 20)           val = wih1r[orow * 20 + k];
                    else if (k <= 29)     val = whh1r[orow * 10 + (k - 20)];
                    else if (k == 30)     val = bih1r[orow] + bhh1r[orow];
                }
                v[s] = val;
            }
        }
        ws[WS_AF + (fid * 64 + l) * 4 + j] = pk_h16(v[0], v[1]);
    }
}

// =================== main: 4 waves x 16 elems, zero barriers, no fences ===================
struct Lds16 {
    u32   bx[4][TT][16][4];    // 20480 B  {x01, x23, x45, PKB} per (t,e)
    float m[4][TT][16];        //  5120 B  mask
    u32   hx[4][2][16][6];     //  3072 B  h pair-slots {01,23,45,67,89,pad}
    u32   zpad[2];             //     8 B  always-zero
};

__global__ __launch_bounds__(256, 4)
void bilstm16(
    const int*   __restrict__ eidx, const float* __restrict__ f,
    const float* __restrict__ emb,  const float* __restrict__ fw,
    const float* __restrict__ fb,
    const u32* __restrict__ wsr, u32* __restrict__ fr,
    float* __restrict__ out)
{
    __shared__ Lds16 lds;
    const int tid  = threadIdx.x;
    const int lane = tid & 63;
    const int e    = lane & 15;
    const int q    = lane >> 4;
    const int wv   = __builtin_amdgcn_readfirstlane(tid >> 6);
    const int g    = blockIdx.x * 4 + wv;
    const int b0   = g * 16;
    const int xaddr16 = (e + 16) << 2;      // bpermute src: quarter-1 lane, same e
    u32* frp = fr + (size_t)g * TT * FR_ROW;

    // ---- wave-local staging (all u32/float typed; no punning) ----
    {
        float fw0=fw[0],fw1=fw[1],fw2=fw[2],fw3=fw[3],fw4=fw[4];
        float fw5=fw[5],fw6=fw[6],fw7=fw[7],fw8=fw[8];
        float fb0=fb[0],fb1=fb[1],fb2=fb[2];
#pragma unroll 1
        for (int it = 0; it < 5; ++it) {
            int idx = lane + it * 64;              // 0..319
            int ee = idx / TT, t = idx - ee * TT;
            int gi = (b0 + ee) * TT + t;
            float f0 = f[gi * 3], f1 = f[gi * 3 + 1], f2v = f[gi * 3 + 2];
            int ei = eidx[gi] * 3;
            float x0 = emb[ei], x1 = emb[ei + 1], x2 = emb[ei + 2];
            float x3 = fmaf(fw0, f0, fmaf(fw1, f1, fmaf(fw2, f2v, fb0)));
            float x4 = fmaf(fw3, f0, fmaf(fw4, f1, fmaf(fw5, f2v, fb1)));
            float x5 = fmaf(fw6, f0, fmaf(fw7, f1, fmaf(fw8, f2v, fb2)));
            lds.bx[wv][t][ee][0] = pk_h16(x0, x1);
            lds.bx[wv][t][ee][1] = pk_h16(x2, x3);
            lds.bx[wv][t][ee][2] = pk_h16(x4, x5);
            lds.bx[wv][t][ee][3] = PKB;
            lds.m[wv][t][ee]     = (f1 != 0.f) ? 1.f : 0.f;
        }
        u32* zz = &lds.hx[wv][0][0][0];            // zero both h buffers (192 u32)
        zz[lane] = 0u; zz[lane + 64] = 0u; zz[lane + 128] = 0u;
        if (lane < 2) lds.zpad[lane] = 0u;
    }

    u32* hxF = &lds.hx[wv][0][e][0];
    u32* hxB = &lds.hx[wv][1][e][0];
    const u32* zp = lds.zpad;
    const u32x4* wv4 = (const u32x4*)(wsr + WS_AF);
    const f32x4v z4 = {};

    // ---- Phase A: fwd + bwd layer-0 chains, interleaved in-wave ----
    // B-frag (blocked-16): q covers k{4q..4q+3}=b[0],b[1] and {16+4q..}=b[2],b[3].
    // fwd/bwd map: q0:{x01,x23 | h89,0}  q1:{x45,PKB | 0,0}
    //              q2:{h01,h23 | 0,0}    q3:{h45,h67 | 0,0}
    {
        u32x4 F0 = wv4[0 * 64 + lane], F1 = wv4[1 * 64 + lane], F2 = wv4[2 * 64 + lane];
        u32x4 G0 = wv4[3 * 64 + lane], G1 = wv4[4 * 64 + lane], G2 = wv4[5 * 64 + lane];
        const u32* aF  = (q < 2) ? &lds.bx[wv][0][e][2 * q]      : &hxF[2 * (q - 2)];
        const u32* aB  = (q < 2) ? &lds.bx[wv][TT - 1][e][2 * q] : &hxB[2 * (q - 2)];
        const u32* a2F = (q == 0) ? &hxF[4] : zp;
        const u32* a2B = (q == 0) ? &hxB[4] : zp;
        const int  strA = (q < 2) ? 64 : 0;        // u32 stride per t (16*4)

        float cF[3] = {0,0,0}, cB[3] = {0,0,0};
#pragma unroll 1
        for (int s = 0; s < TT; ++s) {
            // fwd cell t=s
            u32x4 bf; bf[0] = aF[s * strA]; bf[1] = aF[s * strA + 1];
            bf[2] = *a2F; bf[3] = 0u;
            f32x4v A0 = MFMA16(F0, bf, z4), A1 = MFMA16(F1, bf, z4), A2 = MFMA16(F2, bf, z4);
            // bwd cell t=19-s
            u32x4 bb; bb[0] = aB[-s * strA]; bb[1] = aB[-s * strA + 1];
            bb[2] = *a2B; bb[3] = 0u;
            f32x4v C0 = MFMA16(G0, bb, z4), C1 = MFMA16(G1, bb, z4), C2 = MFMA16(G2, bb, z4);
            // updates: units 2q, 2q+1, 8+q (q<2; pad otherwise)
            float hF[3], hB[3];
            unit_cr(A0[0], A0[1], A0[2], A0[3], &cF[0], &hF[0]);
            unit_cr(A1[0], A1[1], A1[2], A1[3], &cF[1], &hF[1]);
            unit_cr(A2[0], A2[1], A2[2], A2[3], &cF[2], &hF[2]);
            unit_cr(C0[0], C0[1], C0[2], C0[3], &cB[0], &hB[0]);
            unit_cr(C1[0], C1[1], C1[2], C1[3], &cB[1], &hB[1]);
            unit_cr(C2[0], C2[1], C2[2], C2[3], &cB[2], &hB[2]);
            // pair-slot exchange (u32-typed): slot q = {h_2q, h_2q+1}
            u32 pF = pk_h16(hF[0], hF[1]);
            u32 pB = pk_h16(hB[0], hB[1]);
            hxF[q] = pF;
            hxB[q] = pB;
            // slot 4 = {h8,h9}: q0 has h8, pulls h9 from quarter-1 lane (bpermute)
            u32 rF = (u32)__builtin_amdgcn_ds_bpermute(xaddr16, (int)__float_as_uint(hF[2]));
            u32 rB = (u32)__builtin_amdgcn_ds_bpermute(xaddr16, (int)__float_as_uint(hB[2]));
            u32 s4F = pk_h16(hF[2], __uint_as_float(rF));
            u32 s4B = pk_h16(hB[2], __uint_as_float(rB));
            if (q == 0) { hxF[4] = s4F; hxB[4] = s4B; }
            // export CB-ready pairs straight from registers
            u32* frT = frp + s * FR_ROW;
            u32* frB = frp + (TT - 1 - s) * FR_ROW;
            frT[e * 10 + q]     = pF;
            frB[e * 10 + 5 + q] = pB;
            if (q == 0) {
                frT[e * 10 + 4] = s4F;
                frB[e * 10 + 9] = s4B;
            }
        }
    }

    // ---- Phase B: layer-1 backward (K: hf0-9 | hb0-9 | h1_0-9 | bias) ----
    // q0:{hf01,hf23 | hb67,hb89}  q1:{hf45,hf67 | h1_01,h1_23}
    // q2:{hf89,hb01 | h1_45,h1_67}  q3:{hb23,hb45 | h1_89,PKB}
    {
        u32x4 H0 = wv4[6 * 64 + lane], H1 = wv4[7 * 64 + lane], H2 = wv4[8 * 64 + lane];
        // re-zero h1 buffer (hx[wv][0], 96 u32)
        u32* hz = &lds.hx[wv][0][0][0];
        hz[lane] = 0u;
        if (lane < 32) hz[64 + lane] = 0u;
        const u32* caddr = (q == 0) ? zp : &lds.hx[wv][0][e][2 * (q - 1)];
        const int loffA = e * 10 + q * 2;
        const int loffB = e * 10 + 8;
        float cH[3] = {0,0,0}, tot = 0.f;
        u32 La0 = frp[(TT - 1) * FR_ROW + loffA], La1 = frp[(TT - 1) * FR_ROW + loffA + 1];
        u32 Lb0 = frp[(TT - 1) * FR_ROW + loffB], Lb1 = frp[(TT - 1) * FR_ROW + loffB + 1];
#pragma unroll 1
        for (int t = TT - 1; t >= 0; --t) {
            u32 c0 = caddr[0], c1 = caddr[1];
            u32x4 bc;
            bc[0] = La0;
            bc[1] = La1;
            bc[2] = (q == 0) ? Lb0 : c0;
            bc[3] = (q == 0) ? Lb1 : ((q == 3) ? PKB : c1);
            if (t > 0) {                      // prefetch t-1
                La0 = frp[(t - 1) * FR_ROW + loffA]; La1 = frp[(t - 1) * FR_ROW + loffA + 1];
                Lb0 = frp[(t - 1) * FR_ROW + loffB]; Lb1 = frp[(t - 1) * FR_ROW + loffB + 1];
            }
            f32x4v D0 = MFMA16(H0, bc, z4), D1 = MFMA16(H1, bc, z4), D2 = MFMA16(H2, bc, z4);
            float hH[3];
            unit_cr(D0[0], D0[1], D0[2], D0[3], &cH[0], &hH[0]);
            unit_cr(D1[0], D1[1], D1[2], D1[3], &cH[1], &hH[1]);
            unit_cr(D2[0], D2[1], D2[2], D2[3], &cH[2], &hH[2]);
            u32 pH = pk_h16(hH[0], hH[1]);
            hxF[q] = pH;
            u32 rH = (u32)__builtin_amdgcn_ds_bpermute(xaddr16, (int)__float_as_uint(hH[2]));
            if (q == 0) hxF[4] = pk_h16(hH[2], __uint_as_float(rH));
            if (q == 1) {                     // unit 9 = 8+q at q=1 -> hH[2]
                float ip = fmaxf(hH[2] * lds.m[wv][t][e], 0.f);
                out[BB + (b0 + e) * TT + t] = ip;
                tot += ip;
            }
        }
        if (q == 1) out[b0 + e] = tot;
    }
}

// =================== fallback (small ws): verified 32x32 r11 path ===================
__device__ __forceinline__ u32x4 pack_h32(const float* h, bool hi, int xaddr, u32 b3) {
    u32 send = hi ? pk_h16(h[3], h[4]) : __float_as_uint(h[4]);
    u32 recv = (u32)__builtin_amdgcn_ds_bpermute(xaddr, (int)send);
    u32 lo0 = pk_h16(h[0], h[1]), lo1 = pk_h16(h[2], h[3]);
    u32 hi0 = pk_h16(__uint_as_float(recv), h[0]);
    u32 hi1 = pk_h16(h[1], h[2]);
    u32x4 b;
    b[0] = hi ? hi0 : lo0; b[1] = hi ? hi1 : lo1;
    b[2] = hi ? 0u : recv; b[3] = b3;
    return b;
}
__device__ __forceinline__ void cell_update5(const f32x16 a0, const f32x16 a1,
                                             float* c, float* h) {
#pragma unroll
    for (int v = 0; v < 4; ++v)
        unit_cr(a0[v], a0[4 + v], a0[8 + v], a0[12 + v], &c[v], &h[v]);
    unit_cr(a1[0], a1[1], a1[2], a1[3], &c[4], &h[4]);
}
__device__ __forceinline__ int inv_pi(int row) {
    if (row < 32) { int q = row >> 3, rem = row & 7; return q * 10 + 5 * (rem >> 2) + (rem & 3); }
    if (row < 40) { int lo = row - 32; return (lo & 3) * 10 + 5 * (lo >> 2) + 4; }
    return -1;
}
__global__ __launch_bounds__(256)
void prep_old(
    const float* __restrict__ wih0, const float* __restrict__ whh0,
    const float* __restrict__ bih0, const float* __restrict__ bhh0,
    const float* __restrict__ wih0r,const float* __restrict__ whh0r,
    const float* __restrict__ bih0r,const float* __restrict__ bhh0r,
    const float* __restrict__ wih1r,const float* __restrict__ whh1r,
    const float* __restrict__ bih1r,const float* __restrict__ bhh1r,
    u32* __restrict__ ws)
{
    for (int gid = threadIdx.x; gid < 14 * 64 * 4; gid += 256) {
        int fid = gid >> 8, l = (gid >> 2) & 63, j = gid & 3;
        int gq = l >> 5;
        int tile, chunk;
        if (fid < 8) { tile = (fid >> 1) & 1; chunk = fid & 1; }
        else         { int q2 = fid - 8; tile = q2 / 3; chunk = q2 % 3; }
        int row = tile * 32 + (l & 31);
        int orow = inv_pi(row);
        int kb = (j >> 1) * 8 + 4 * gq + (j & 1) * 2;
        float v[2] = {0.f, 0.f};
        if (orow >= 0) {
#pragma unroll
            for (int s = 0; s < 2; ++s) {
                int k = kb + s;
                float val = 0.f;
                if (fid < 8) {
                    bool bwd = fid >= 4;
                    if (chunk == 0) {
                        if (k < 6)       val = (bwd ? wih0r : wih0)[orow * 6 + k];
                        else if (k == 6) val = (bwd ? bih0r[orow] + bhh0r[orow]
                                                    : bih0[orow] + bhh0[orow]);
                    } else { if (k < 10) val = (bwd ? whh0r : whh0)[orow * 10 + k]; }
                } else {
                    if (chunk == 0)      { if (k < 10) val = wih1r[orow * 20 + k]; }
                    else if (chunk == 1) { if (k < 10) val = wih1r[orow * 20 + 10 + k]; }
                    else {
                        if (k < 10)       val = whh1r[orow * 10 + k];
                        else if (k == 10) val = bih1r[orow] + bhh1r[orow];
                    }
                }
                v[s] = val;
            }
        }
        ws[WS_OLD + (fid * 64 + l) * 4 + j] = pk_h16(v[0], v[1]);
    }
}
struct LdsFB { u32 x[TT][3][32]; float m[TT][32]; u32 hf[TT][160]; };
__global__ __launch_bounds__(64)
void bilstm_fb(
    const int*   __restrict__ eidx, const float* __restrict__ f,
    const float* __restrict__ emb,  const float* __restrict__ fw,
    const float* __restrict__ fb,
    const u32* __restrict__ wsr, float* __restrict__ out)
{
    __shared__ LdsFB lds;
    const int  lane = threadIdx.x;
    const int  e    = lane & 31;
    const bool hi   = lane >= 32;
    const int  wid  = blockIdx.x;
    const int  b0   = wid * 32;
    const int  xaddr = (lane ^ 32) << 2;
    {
        float fw0=fw[0],fw1=fw[1],fw2=fw[2],fw3=fw[3],fw4=fw[4];
        float fw5=fw[5],fw6=fw[6],fw7=fw[7],fw8=fw[8];
        float fb0=fb[0],fb1=fb[1],fb2=fb[2];
#pragma unroll 1
        for (int it = 0; it < 10; ++it) {
            int idx = lane + it * 64;
            int ee = idx / 20, t = idx - ee * 20;
            int gi = (b0 + ee) * TT + t;
            float f0 = f[gi * 3], f1 = f[gi * 3 + 1], f2v = f[gi * 3 + 2];
            int ei = eidx[gi] * 3;
            float x0 = emb[ei], x1 = emb[ei + 1], x2 = emb[ei + 2];
            float x3 = fmaf(fw0, f0, fmaf(fw1, f1, fmaf(fw2, f2v, fb0)));
            float x4 = fmaf(fw3, f0, fmaf(fw4, f1, fmaf(fw5, f2v, fb1)));
            float x5 = fmaf(fw6, f0, fmaf(fw7, f1, fmaf(fw8, f2v, fb2)));
            lds.x[t][0][ee] = pk_h16(x0, x1);
            lds.x[t][1][ee] = pk_h16(x2, x3);
            lds.x[t][2][ee] = pk_h16(x4, x5);
            lds.m[t][ee]    = (f1 != 0.f) ? 1.f : 0.f;
        }
    }
    const u32x4* wv = (const u32x4*)(wsr + WS_OLD);
    const f32x16 zf = {};
    {
        u32x4 wf0 = wv[0 * 64 + lane], wf1 = wv[1 * 64 + lane];
        u32x4 wf2 = wv[2 * 64 + lane], wf3 = wv[3 * 64 + lane];
        float cf[5] = {0,0,0,0,0}, hv[5] = {0,0,0,0,0};
        u32x4 bx0;
        {
            u32 x01 = lds.x[0][0][e], x23 = lds.x[0][1][e], x45 = lds.x[0][2][e];
            bx0[0] = hi ? x45 : x01; bx0[1] = hi ? PKB : x23; bx0[2] = 0u; bx0[3] = 0u;
        }
        f32x16 a0x = MFMA32(wf0, bx0, zf);
        f32x16 a1x = MFMA32(wf2, bx0, zf);
        u32x4 bh;
#pragma unroll 1
        for (int t = 0; t < TT; ++t) {
            f32x16 a0 = a0x, a1 = a1x;
            if (t > 0) { a0 = MFMA32(wf1, bh, a0); a1 = MFMA32(wf3, bh, a1); }
            if (t + 1 < TT) {
                u32 x01 = lds.x[t+1][0][e], x23 = lds.x[t+1][1][e], x45 = lds.x[t+1][2][e];
                u32x4 bx; bx[0] = hi ? x45 : x01; bx[1] = hi ? PKB : x23; bx[2] = 0u; bx[3] = 0u;
                a0x = MFMA32(wf0, bx, zf);
                a1x = MFMA32(wf2, bx, zf);
            }
            cell_update5(a0, a1, cf, hv);
            bh = pack_h32(hv, hi, xaddr, 0u);
            lds.hf[t][lane * 2] = bh[0]; lds.hf[t][lane * 2 + 1] = bh[1];
            if (!hi) lds.hf[t][128 + e] = bh[2];
        }
    }
    {
        u32x4 wb0 = wv[4 * 64 + lane], wb1 = wv[5 * 64 + lane];
        u32x4 wb2 = wv[6 * 64 + lane], wb3 = wv[7 * 64 + lane];
        u32x4 wB0 = wv[8 * 64 + lane], wB1 = wv[9 * 64 + lane], wB2 = wv[10 * 64 + lane];
        u32x4 wB3 = wv[11 * 64 + lane], wB4 = wv[12 * 64 + lane], wB5 = wv[13 * 64 + lane];
        float cb[5] = {0,0,0,0,0}, hbv[5] = {0,0,0,0,0};
        float cc[5] = {0,0,0,0,0}, h1v[5] = {0,0,0,0,0};
        float tot = 0.f;
        {
            u32 x01 = lds.x[TT-1][0][e], x23 = lds.x[TT-1][1][e], x45 = lds.x[TT-1][2][e];
            u32x4 bx; bx[0] = hi ? x45 : x01; bx[1] = hi ? PKB : x23; bx[2] = 0u; bx[3] = 0u;
            f32x16 a0 = MFMA32(wb0, bx, zf);
            f32x16 a1 = MFMA32(wb2, bx, zf);
            cell_update5(a0, a1, cb, hbv);
        }
        uint2 cur2 = make_uint2(lds.hf[TT-1][lane * 2], lds.hf[TT-1][lane * 2 + 1]);
        u32   curw = lds.hf[TT-1][128 + e];
#pragma unroll 1
        for (int t = TT - 1; t >= 1; --t) {
            uint2 nxt2 = make_uint2(lds.hf[t-1][lane * 2], lds.hf[t-1][lane * 2 + 1]);
            u32   nxtw = lds.hf[t-1][128 + e];
            u32x4 shared = pack_h32(hbv, hi, xaddr, 0u);
            u32x4 bh1    = pack_h32(h1v, hi, xaddr, hi ? 0u : PKB);
            u32x4 bhf; bhf[0] = cur2.x; bhf[1] = cur2.y; bhf[2] = hi ? 0u : curw; bhf[3] = 0u;
            f32x16 B0 = MFMA32(wB0, bhf, zf); B0 = MFMA32(wB1, shared, B0); B0 = MFMA32(wB2, bh1, B0);
            f32x16 B1 = MFMA32(wB3, bhf, zf); B1 = MFMA32(wB4, shared, B1); B1 = MFMA32(wB5, bh1, B1);
            u32 x01 = lds.x[t-1][0][e], x23 = lds.x[t-1][1][e], x45 = lds.x[t-1][2][e];
            u32x4 bx; bx[0] = hi ? x45 : x01; bx[1] = hi ? PKB : x23; bx[2] = 0u; bx[3] = 0u;
            f32x16 A0 = MFMA32(wb0, bx, zf); A0 = MFMA32(wb1, shared, A0);
            f32x16 A1 = MFMA32(wb2, bx, zf); A1 = MFMA32(wb3, shared, A1);
            cell_update5(B0, B1, cc, h1v);
            if (hi) {
                float ip = fmaxf(h1v[4] * lds.m[t][e], 0.f);
                out[BB + (b0 + e) * TT + t] = ip;
                tot += ip;
            }
            cell_update5(A0, A1, cb, hbv);
            cur2 = nxt2; curw = nxtw;
        }
        {
            u32x4 shared = pack_h32(hbv, hi, xaddr, 0u);
            u32x4 bh1    = pack_h32(h1v, hi, xaddr, hi ? 0u : PKB);
            u32x4 bhf; bhf[0] = cur2.x; bhf[1] = cur2.y; bhf[2] = hi ? 0u : curw; bhf[3] = 0u;
            f32x16 B0 = MFMA32(wB0, bhf, zf); B0 = MFMA32(wB1, shared, B0); B0 = MFMA32(wB2, bh1, B0);
            f32x16 B1 = MFMA32(wB3, bhf, zf); B1 = MFMA32(wB4, shared, B1); B1 = MFMA32(wB5, bh1, B1);
            cell_update5(B0, B1, cc, h1v);
            if (hi) {
                float ip = fmaxf(h1v[4] * lds.m[0][e], 0.f);
                out[BB + (b0 + e) * TT + 0] = ip;
                tot += ip;
                out[b0 + e] = tot;
            }
        }
    }
}

extern "C" void kernel_launch(void* const* d_in, const int* in_sizes, int n_in,
                              void* d_out, int out_size, void* d_ws, size_t ws_size,
                              hipStream_t stream) {
    const int*   eidx  = (const int*)  d_in[0];
    const float* f     = (const float*)d_in[1];
    const float* emb   = (const float*)d_in[2];
    const float* fw    = (const float*)d_in[3];
    const float* fb    = (const float*)d_in[4];
    const float* wih0  = (const float*)d_in[5];
    const float* whh0  = (const float*)d_in[6];
    const float* bih0  = (const float*)d_in[7];
    const float* bhh0  = (const float*)d_in[8];
    const float* wih0r = (const float*)d_in[9];
    const float* whh0r = (const float*)d_in[10];
    const float* bih0r = (const float*)d_in[11];
    const float* bhh0r = (const float*)d_in[12];
    // d_in[13..16] = layer-1 forward weights: dead (output uses only bwd unit 9)
    const float* wih1r = (const float*)d_in[17];
    const float* whh1r = (const float*)d_in[18];
    const float* bih1r = (const float*)d_in[19];
    const float* bhh1r = (const float*)d_in[20];
    float* out = (float*)d_out;
    u32* ws = (u32*)d_ws;

    const size_t need16 = (size_t)(WS_FR + (size_t)NG16 * TT * FR_ROW + 64) * 4;
    if (ws_size >= need16) {
        hipLaunchKernelGGL(prep16, dim3(1), dim3(256), 0, stream,
                           wih0, whh0, bih0, bhh0, wih0r, whh0r, bih0r, bhh0r,
                           wih1r, whh1r, bih1r, bhh1r, ws);
        hipLaunchKernelGGL(bilstm16, dim3(NG16 / 4), dim3(256), 0, stream,
                           eidx, f, emb, fw, fb, ws, ws + WS_FR, out);
    } else {
        hipLaunchKernelGGL(prep_old, dim3(1), dim3(256), 0, stream,
                           wih0, whh0, bih0, bhh0, wih0r, whh0r, bih0r, bhh0r,
                           wih1r, whh1r, bih1r, bhh1r, ws);
        hipLaunchKernelGGL(bilstm_fb, dim3(BB / 32), dim3(64), 0, stream,
                           eidx, f, emb, fw, fb, ws, out);
    }
}